// Round 4
// baseline (756.566 us; speedup 1.0000x reference)
//
#include <hip/hip_runtime.h>

#define NN 8192
#define CC 512
#define DKK 64

typedef float f32x4 __attribute__((ext_vector_type(4)));
typedef float f32x16 __attribute__((ext_vector_type(16)));
typedef _Float16 f16x8 __attribute__((ext_vector_type(8)));
typedef _Float16 f16x4 __attribute__((ext_vector_type(4)));

__device__ __forceinline__ f32x4 mfma16(f16x8 a, f16x8 b, f32x4 c) {
    return __builtin_amdgcn_mfma_f32_16x16x32_f16(a, b, c, 0, 0, 0);
}
__device__ __forceinline__ f32x16 mfma32(f16x8 a, f16x8 b, f32x16 c) {
    return __builtin_amdgcn_mfma_f32_32x32x16_f16(a, b, c, 0, 0, 0);
}
__device__ __forceinline__ f16x8 sclh8(f16x8 v, _Float16 h) {
    f16x8 r;
#pragma unroll
    for (int i = 0; i < 8; i++) r[i] = v[i] * h;
    return r;
}
#if __has_builtin(__builtin_amdgcn_exp2f)
__device__ __forceinline__ float exp2fast(float x) { return __builtin_amdgcn_exp2f(x); }
#else
__device__ __forceinline__ float exp2fast(float x) { return exp2f(x); }
#endif

// ---- all weight transposes in one launch. grid 1280 x 256.
__global__ void wtrans_all_kernel(const float* __restrict__ Wq, const float* __restrict__ Wk,
                                  const float* __restrict__ Wv,
                                  _Float16* __restrict__ Wqt, _Float16* __restrict__ Wkt,
                                  _Float16* __restrict__ Wvf) {
    int idx = blockIdx.x * 256 + threadIdx.x;
    if (idx < 32768) {
        int n = idx >> 9, k = idx & 511;
        Wqt[idx] = (_Float16)Wq[k * 64 + n];
    } else if (idx < 65536) {
        int j = idx - 32768;
        int n = j >> 9, k = j & 511;
        Wkt[j] = (_Float16)Wk[k * 64 + n];
    } else {
        int j = idx - 65536;
        int k16 = j & 15, c = (j >> 4) & 511, ks = j >> 13;
        Wvf[j] = (_Float16)Wv[(size_t)(16 * ks + k16) * 512 + c];
    }
}

// ---- fused Q+K projection: Q[N][64] row-major f16 (PRE-SCALED by log2(e) so the
// flash softmax runs in the exp2 domain: one v_exp_f32 per element, no mul);
// K -> frag-major Kf[tile=n>>6][ks=dk>>4][kv6=n&63][k16=dk&15]
__global__ __launch_bounds__(256) void proj_qk2_kernel(
    const float* __restrict__ im1, const float* __restrict__ im2,
    const _Float16* __restrict__ Wqt, const _Float16* __restrict__ Wkt,
    _Float16* __restrict__ Q1, _Float16* __restrict__ Kf1,
    _Float16* __restrict__ Q2, _Float16* __restrict__ Kf2)
{
    const float* X = blockIdx.y ? im2 : im1;
    _Float16* Q = blockIdx.y ? Q2 : Q1;
    _Float16* Kf = blockIdx.y ? Kf2 : Kf1;

    __shared__ __align__(16) _Float16 Wlds[128 * 512];  // 128 KB

    const int tid = threadIdx.x;
    const int lane = tid & 63, wave = tid >> 6;
    const int n16 = lane & 15, quad = lane >> 4;

#pragma unroll
    for (int i = 0; i < 32; i++) {
        const int idx = tid + 256 * i;
        const int row = idx >> 6, ch = idx & 63;
        const _Float16* src = (row < 64) ? (Wqt + (size_t)row * 512 + ch * 8)
                                         : (Wkt + (size_t)(row - 64) * 512 + ch * 8);
        *(f16x8*)&Wlds[row * 512 + ((ch ^ (row & 7)) * 8)] = *(const f16x8*)src;
    }
    __syncthreads();

    const int arow = blockIdx.x * 64 + wave * 16 + n16;
    f32x4 acc[8];
#pragma unroll
    for (int i = 0; i < 8; i++) acc[i] = (f32x4){0.f, 0.f, 0.f, 0.f};

    const float* xbase = X + (size_t)arow * 512 + quad * 8;
    for (int kk = 0; kk < 16; kk++) {
        f32x4 xa = *(const f32x4*)(xbase + kk * 32);
        f32x4 xb = *(const f32x4*)(xbase + kk * 32 + 4);
        f16x8 afrag;
#pragma unroll
        for (int j = 0; j < 4; j++) { afrag[j] = (_Float16)xa[j]; afrag[4 + j] = (_Float16)xb[j]; }
#pragma unroll
        for (int t = 0; t < 8; t++) {
            const int row = t * 16 + n16;
            f16x8 bfr = *(const f16x8*)&Wlds[row * 512 + (((4 * kk + quad) ^ (row & 7)) * 8)];
            acc[t] = mfma16(afrag, bfr, acc[t]);
        }
    }
    const int rbase = blockIdx.x * 64 + wave * 16 + quad * 4;
#pragma unroll
    for (int t = 0; t < 4; t++)
#pragma unroll
        for (int r = 0; r < 4; r++) {
            Q[(size_t)(rbase + r) * 64 + t * 16 + n16] = (_Float16)(acc[t][r] * 1.44269504f);
            Kf[((size_t)(blockIdx.x * 4 + t) * 64 + (wave * 16 + quad * 4 + r)) * 16 + n16] =
                (_Float16)acc[4 + t][r];
        }
}

// ---- V projection -> frag-major Vf[tile][ks=n6>>4][c=512][n16]
__global__ __launch_bounds__(256) void proj_vt_kernel(
    const float* __restrict__ im1, const float* __restrict__ im2,
    const _Float16* __restrict__ Wvf,
    _Float16* __restrict__ Vf1, _Float16* __restrict__ Vf2)
{
    const float* X = blockIdx.y ? im2 : im1;
    _Float16* Vf = blockIdx.y ? Vf2 : Vf1;
    const int n0 = blockIdx.x * 32;
    const int tid = threadIdx.x;
    const int lane = tid & 63, wave = tid >> 6;
    const int l31 = lane & 31, lhi = lane >> 5;

    __shared__ __align__(16) _Float16 Xlds[32 * 512];

#pragma unroll
    for (int i = 0; i < 8; i++) {
        const int n = tid >> 3;
        const int chunk = (tid & 7) + 8 * i;
        const float* xp = X + (size_t)(n0 + n) * CC + chunk * 8;
        f32x4 x0 = *(const f32x4*)xp;
        f32x4 x1 = *(const f32x4*)(xp + 4);
        f16x8 d;
#pragma unroll
        for (int j = 0; j < 4; j++) { d[j] = (_Float16)x0[j]; d[4 + j] = (_Float16)x1[j]; }
        *(f16x8*)&Xlds[n * 512 + ((chunk ^ (n & 7)) * 8)] = d;
    }
    __syncthreads();

    f32x16 acc[4];
#pragma unroll
    for (int t = 0; t < 4; t++)
#pragma unroll
        for (int r = 0; r < 16; r++) acc[t][r] = 0.f;

    for (int ks = 0; ks < 32; ks++) {
        f16x8 xb = *(const f16x8*)&Xlds[l31 * 512 + (((2 * ks + lhi) ^ (l31 & 7)) * 8)];
#pragma unroll
        for (int ct = 0; ct < 4; ct++) {
            const _Float16* wp = Wvf + ((size_t)ks * 512 + 128 * wave + 32 * ct + l31) * 16 + 8 * lhi;
            acc[ct] = mfma32(*(const f16x8*)wp, xb, acc[ct]);
        }
    }
    const int tile = n0 >> 6;
    const int ksbase = (n0 & 32) >> 4;  // 0 or 2
#pragma unroll
    for (int ct = 0; ct < 4; ct++)
#pragma unroll
        for (int r = 0; r < 16; r++) {
            const int c = 128 * wave + 32 * ct + (r & 3) + 8 * (r >> 2) + 4 * lhi;
            const int ks = ksbase + (l31 >> 4);
            Vf[((size_t)(tile * 4 + ks) * 512 + c) * 16 + (l31 & 15)] = (_Float16)acc[ct][r];
        }
}

// ---- flash8: producer/consumer wave specialization (m114 co-schedule: MFMA and
// VALU pipes overlap ACROSS waves, not within one). flash6 geometry: 32-q blocks,
// grid (256,2), 8 waves, 2 blocks/CU, 16 waves/CU; streams = (tile g, kv-half a2)
// = 8, identical math to flash6. Roles: 4 QK waves do all softmax VALU (one
// 64kv-tile each, a2-halves SEQUENTIAL so only one f32x16 is live -> register
// union acc(64)+QK(~50) fits 128); 4 PV waves own 128 cols x 32 q (acc 4xf32x16)
// and do 64 of 72 MFMAs/slot + the 8-stream merge. role=(w^(w>>2))&1 interleaves
// QK/PV on each SIMD under BOTH i%4 and i>>1 wave->SIMD mappings; gid=w>>1.
// exp2-domain softmax (Q pre-scaled by log2e): every exp is one v_exp_f32.
__global__ __launch_bounds__(512, 4) void flash8_kernel(
    const _Float16* __restrict__ Q1, const _Float16* __restrict__ Kf1,
    const _Float16* __restrict__ Q2, const _Float16* __restrict__ Kf2,
    const _Float16* __restrict__ Vf1, const _Float16* __restrict__ Vf2,
    const float* __restrict__ im1, const float* __restrict__ im2,
    float* __restrict__ out)
{
    const int img = blockIdx.y;
    const _Float16* Q = img ? Q1 : Q2;
    const _Float16* Kf = img ? Kf2 : Kf1;
    const _Float16* Vf = img ? Vf2 : Vf1;
    const float* res = img ? im2 : im1;
    float* o = out + (size_t)img * NN * CC;
    const int qbase = blockIdx.x * 32;

    // P[buf][g=tile][chunk=kv>>3][q=32][kv&7] f16, chunk-major = 32 KB
    __shared__ __align__(16) _Float16 P[2][4][8][32][8];
    __shared__ float mPart[2][4][2][32];  // [buf][g][a2][q] per-stream running max
    __shared__ float mF[4][2][32], lF[4][2][32];

    const int tid = threadIdx.x;
    const int lane = tid & 63, w = tid >> 6;
    const int l31 = lane & 31, lhi = lane >> 5;
    const int role = (w ^ (w >> 2)) & 1;  // 0 = QK producer, 1 = PV consumer
    const int gid = w >> 1;               // QK: tile stream; PV: 128-col block

    // ---- QK state
    f16x8 qf[4];
    float ma_run[2] = {-3e38f, -3e38f}, l_run[2] = {0.f, 0.f};
    // ---- PV state
    f32x16 acc[4];
    float mg_run = -3e38f;

    if (role == 0) {
        const _Float16* qp = Q + (size_t)(qbase + l31) * DKK + 8 * lhi;
#pragma unroll
        for (int k = 0; k < 4; k++) qf[k] = *(const f16x8*)(qp + 16 * k);
    } else {
#pragma unroll
        for (int t = 0; t < 4; t++)
#pragma unroll
            for (int r = 0; r < 16; r++) acc[t][r] = 0.f;
    }

    const _Float16* kb = Kf + (size_t)l31 * 16 + 8 * lhi;
    const _Float16* vb = Vf + (size_t)(128 * gid + l31) * 16 + 8 * lhi;

    // QK for slot s, tile t=4s+gid: two sequential kv-halves (a2), own running
    // max/sum per (gid,a2) stream, chunk-major P write. Peak live: ONE f32x16.
    auto do_qk = [&](int s) {
        const int t = 4 * s + gid;
        const int pbuf = s & 1;
#pragma unroll
        for (int a2 = 0; a2 < 2; a2++) {
            f32x16 sA;
#pragma unroll
            for (int r = 0; r < 16; r++) sA[r] = 0.f;
#pragma unroll
            for (int k = 0; k < 4; k++) {
                f16x8 kf = *(const f16x8*)(kb + (size_t)((t * 4 + k) * 64 + 32 * a2) * 16);
                sA = mfma32(kf, qf[k], sA);
            }
            float mr[8];
#pragma unroll
            for (int i = 0; i < 8; i++) mr[i] = fmaxf(sA[i], sA[i + 8]);
#pragma unroll
            for (int i = 0; i < 4; i++) mr[i] = fmaxf(mr[i], mr[i + 4]);
            float mx = fmaxf(fmaxf(mr[0], mr[1]), fmaxf(mr[2], mr[3]));
            mx = fmaxf(mx, __shfl_xor(mx, 32));
            const float manew = fmaxf(ma_run[a2], mx);
            if (lane < 32) mPart[pbuf][gid][a2][lane] = manew;
            float ls = 0.f;
#pragma unroll
            for (int r = 0; r < 16; r++) {
                float p = exp2fast(sA[r] - manew);
                ls += p;
                sA[r] = p;
            }
            ls += __shfl_xor(ls, 32);
            l_run[a2] = l_run[a2] * exp2fast(ma_run[a2] - manew) + ls;
            ma_run[a2] = manew;
            // kv_local = (r&3) + 8*(r>>2) + 4*lhi + 32*a2 -> chunk 4*a2+(r>>2)
#pragma unroll
            for (int gg = 0; gg < 4; gg++) {
                f16x4 p4;
#pragma unroll
                for (int u = 0; u < 4; u++) p4[u] = (_Float16)sA[gg * 4 + u];
                *(f16x4*)&P[pbuf][gid][4 * a2 + gg][l31][4 * lhi] = p4;
            }
        }
    };

    if (role == 0) do_qk(0);
    __syncthreads();

    for (int s = 0; s < 32; s++) {
        const int pbuf = s & 1;
        if (role == 0) {
            if (s < 31) do_qk(s + 1);  // writes other P buffer
        } else {
            // prefetch V (tt=0,k=0) for all 4 ct: covers L2 latency under merge
            f16x8 va_pre[4];
#pragma unroll
            for (int ct = 0; ct < 4; ct++)
                va_pre[ct] = *(const f16x8*)(vb + (size_t)((4 * s) * 4 * 512 + 32 * ct * 512 / 512 * 512) * 0 +
                                             (size_t)((4 * s) * 4 * 512 + 32 * ct) * 16);
            // ---- merge 8 (g,a2) streams
            float m[4][2];
            float mgn = mg_run;
#pragma unroll
            for (int g2 = 0; g2 < 4; g2++)
#pragma unroll
                for (int a2 = 0; a2 < 2; a2++) {
                    m[g2][a2] = mPart[pbuf][g2][a2][l31];
                    mgn = fmaxf(mgn, m[g2][a2]);
                }
            const float al = exp2fast(mg_run - mgn);
            mg_run = mgn;
            _Float16 fh[4][2];
#pragma unroll
            for (int g2 = 0; g2 < 4; g2++)
#pragma unroll
                for (int a2 = 0; a2 < 2; a2++)
                    fh[g2][a2] = (_Float16)exp2fast(m[g2][a2] - mgn);
            if (!__all(al == 1.f)) {
#pragma unroll
                for (int t = 0; t < 4; t++)
#pragma unroll
                    for (int r = 0; r < 16; r++) acc[t][r] *= al;
            }
            // ---- PV: 16 P reads, 64 V loads, 64 mfma
#pragma unroll
            for (int tt = 0; tt < 4; tt++) {
                const int t = 4 * s + tt;
#pragma unroll
                for (int k = 0; k < 4; k++) {
                    f16x8 pb = *(const f16x8*)&P[pbuf][tt][2 * k + lhi][l31][0];
                    pb = sclh8(pb, fh[tt][k >> 1]);
#pragma unroll
                    for (int ct = 0; ct < 4; ct++) {
                        f16x8 va = (tt == 0 && k == 0) ? va_pre[ct]
                            : *(const f16x8*)(vb + (size_t)((t * 4 + k) * 512 + 32 * ct) * 16);
                        acc[ct] = mfma32(va, pb, acc[ct]);
                    }
                }
            }
        }
        __syncthreads();  // P(s+1)/mPart(s+1) written; P(s) reads done
    }

    if (role == 0 && lane < 32) {
#pragma unroll
        for (int a2 = 0; a2 < 2; a2++) {
            mF[gid][a2][lane] = ma_run[a2];
            lF[gid][a2][lane] = l_run[a2];
        }
    }
    __syncthreads();

    if (role == 1) {
        const float M = mg_run;  // max over all 8 final stream maxima (monotone)
        float den = 0.f;
#pragma unroll
        for (int g2 = 0; g2 < 4; g2++)
#pragma unroll
            for (int a2 = 0; a2 < 2; a2++)
                den += lF[g2][a2][l31] * exp2fast(mF[g2][a2][l31] - M);
        const float fac = 1.f / den;
#pragma unroll
        for (int ct = 0; ct < 4; ct++)
#pragma unroll
            for (int rg = 0; rg < 4; rg++) {
                const int c = 128 * gid + 32 * ct + 8 * rg + 4 * lhi;
                const size_t off = (size_t)(qbase + l31) * CC + c;
                f32x4 v;
#pragma unroll
                for (int u = 0; u < 4; u++) v[u] = acc[ct][4 * rg + u] * fac;
                f32x4 r4 = *(const f32x4*)(res + off);
                *(f32x4*)(o + off) = v + r4;
            }
    }
}

extern "C" void kernel_launch(void* const* d_in, const int* in_sizes, int n_in,
                              void* d_out, int out_size, void* d_ws, size_t ws_size,
                              hipStream_t stream) {
    const float* im1 = (const float*)d_in[0];
    const float* im2 = (const float*)d_in[1];
    const float* Wq  = (const float*)d_in[2];
    const float* Wk  = (const float*)d_in[3];
    const float* Wv  = (const float*)d_in[4];
    float* out = (float*)d_out;

    _Float16* w = (_Float16*)d_ws;
    _Float16* Wqt = w;                      // 64*512
    _Float16* Wkt = Wqt + 64 * 512;
    _Float16* Wvf = Wkt + 64 * 512;         // 512*512 frag-major
    _Float16* Q1  = Wvf + 512 * 512;        // 8192*64 each
    _Float16* Kf1 = Q1 + NN * DKK;
    _Float16* Q2  = Kf1 + NN * DKK;
    _Float16* Kf2 = Q2 + NN * DKK;
    _Float16* Vf1 = Kf2 + NN * DKK;         // frag-major [128][4][512][16] each
    _Float16* Vf2 = Vf1 + (size_t)CC * NN;

    wtrans_all_kernel<<<1280, 256, 0, stream>>>(Wq, Wk, Wv, Wqt, Wkt, Wvf);
    proj_qk2_kernel<<<dim3(128, 2), 256, 0, stream>>>(im1, im2, Wqt, Wkt, Q1, Kf1, Q2, Kf2);
    proj_vt_kernel<<<dim3(256, 2), 256, 0, stream>>>(im1, im2, Wvf, Vf1, Vf2);
    flash8_kernel<<<dim3(256, 2), 512, 0, stream>>>(Q1, Kf1, Q2, Kf2, Vf1, Vf2, im1, im2, out);
}

// Round 5
// 439.398 us; speedup vs baseline: 1.7218x; 1.7218x over previous
//
#include <hip/hip_runtime.h>

#define NN 8192
#define CC 512
#define DKK 64

typedef float f32x4 __attribute__((ext_vector_type(4)));
typedef float f32x16 __attribute__((ext_vector_type(16)));
typedef _Float16 f16x8 __attribute__((ext_vector_type(8)));
typedef _Float16 f16x4 __attribute__((ext_vector_type(4)));

__device__ __forceinline__ f32x4 mfma16(f16x8 a, f16x8 b, f32x4 c) {
    return __builtin_amdgcn_mfma_f32_16x16x32_f16(a, b, c, 0, 0, 0);
}
__device__ __forceinline__ f32x16 mfma32(f16x8 a, f16x8 b, f32x16 c) {
    return __builtin_amdgcn_mfma_f32_32x32x16_f16(a, b, c, 0, 0, 0);
}
__device__ __forceinline__ f16x8 sclh8(f16x8 v, _Float16 h) {
    f16x8 r;
#pragma unroll
    for (int i = 0; i < 8; i++) r[i] = v[i] * h;
    return r;
}
__device__ __forceinline__ float exp2fast(float x) { return __builtin_exp2f(x); }

// ---- all weight transposes in one launch. grid 1280 x 256.
__global__ void wtrans_all_kernel(const float* __restrict__ Wq, const float* __restrict__ Wk,
                                  const float* __restrict__ Wv,
                                  _Float16* __restrict__ Wqt, _Float16* __restrict__ Wkt,
                                  _Float16* __restrict__ Wvf) {
    int idx = blockIdx.x * 256 + threadIdx.x;
    if (idx < 32768) {
        int n = idx >> 9, k = idx & 511;
        Wqt[idx] = (_Float16)Wq[k * 64 + n];
    } else if (idx < 65536) {
        int j = idx - 32768;
        int n = j >> 9, k = j & 511;
        Wkt[j] = (_Float16)Wk[k * 64 + n];
    } else {
        int j = idx - 65536;
        int k16 = j & 15, c = (j >> 4) & 511, ks = j >> 13;
        Wvf[j] = (_Float16)Wv[(size_t)(16 * ks + k16) * 512 + c];
    }
}

// ---- fused Q+K projection: Q[N][64] row-major f16 (PRE-SCALED by log2(e): flash
// softmax runs in the exp2 domain, one v_exp_f32 per element);
// K -> frag-major Kf[tile=n>>6][ks=dk>>4][kv6=n&63][k16=dk&15]
__global__ __launch_bounds__(256) void proj_qk2_kernel(
    const float* __restrict__ im1, const float* __restrict__ im2,
    const _Float16* __restrict__ Wqt, const _Float16* __restrict__ Wkt,
    _Float16* __restrict__ Q1, _Float16* __restrict__ Kf1,
    _Float16* __restrict__ Q2, _Float16* __restrict__ Kf2)
{
    const float* X = blockIdx.y ? im2 : im1;
    _Float16* Q = blockIdx.y ? Q2 : Q1;
    _Float16* Kf = blockIdx.y ? Kf2 : Kf1;

    __shared__ __align__(16) _Float16 Wlds[128 * 512];  // 128 KB

    const int tid = threadIdx.x;
    const int lane = tid & 63, wave = tid >> 6;
    const int n16 = lane & 15, quad = lane >> 4;

#pragma unroll
    for (int i = 0; i < 32; i++) {
        const int idx = tid + 256 * i;
        const int row = idx >> 6, ch = idx & 63;
        const _Float16* src = (row < 64) ? (Wqt + (size_t)row * 512 + ch * 8)
                                         : (Wkt + (size_t)(row - 64) * 512 + ch * 8);
        *(f16x8*)&Wlds[row * 512 + ((ch ^ (row & 7)) * 8)] = *(const f16x8*)src;
    }
    __syncthreads();

    const int arow = blockIdx.x * 64 + wave * 16 + n16;
    f32x4 acc[8];
#pragma unroll
    for (int i = 0; i < 8; i++) acc[i] = (f32x4){0.f, 0.f, 0.f, 0.f};

    const float* xbase = X + (size_t)arow * 512 + quad * 8;
    for (int kk = 0; kk < 16; kk++) {
        f32x4 xa = *(const f32x4*)(xbase + kk * 32);
        f32x4 xb = *(const f32x4*)(xbase + kk * 32 + 4);
        f16x8 afrag;
#pragma unroll
        for (int j = 0; j < 4; j++) { afrag[j] = (_Float16)xa[j]; afrag[4 + j] = (_Float16)xb[j]; }
#pragma unroll
        for (int t = 0; t < 8; t++) {
            const int row = t * 16 + n16;
            f16x8 bfr = *(const f16x8*)&Wlds[row * 512 + (((4 * kk + quad) ^ (row & 7)) * 8)];
            acc[t] = mfma16(afrag, bfr, acc[t]);
        }
    }
    const int rbase = blockIdx.x * 64 + wave * 16 + quad * 4;
#pragma unroll
    for (int t = 0; t < 4; t++)
#pragma unroll
        for (int r = 0; r < 4; r++) {
            Q[(size_t)(rbase + r) * 64 + t * 16 + n16] = (_Float16)(acc[t][r] * 1.44269504f);
            Kf[((size_t)(blockIdx.x * 4 + t) * 64 + (wave * 16 + quad * 4 + r)) * 16 + n16] =
                (_Float16)acc[4 + t][r];
        }
}

// ---- V projection -> frag-major Vf[tile][ks=n6>>4][c=512][n16]
__global__ __launch_bounds__(256) void proj_vt_kernel(
    const float* __restrict__ im1, const float* __restrict__ im2,
    const _Float16* __restrict__ Wvf,
    _Float16* __restrict__ Vf1, _Float16* __restrict__ Vf2)
{
    const float* X = blockIdx.y ? im2 : im1;
    _Float16* Vf = blockIdx.y ? Vf2 : Vf1;
    const int n0 = blockIdx.x * 32;
    const int tid = threadIdx.x;
    const int lane = tid & 63, wave = tid >> 6;
    const int l31 = lane & 31, lhi = lane >> 5;

    __shared__ __align__(16) _Float16 Xlds[32 * 512];

#pragma unroll
    for (int i = 0; i < 8; i++) {
        const int n = tid >> 3;
        const int chunk = (tid & 7) + 8 * i;
        const float* xp = X + (size_t)(n0 + n) * CC + chunk * 8;
        f32x4 x0 = *(const f32x4*)xp;
        f32x4 x1 = *(const f32x4*)(xp + 4);
        f16x8 d;
#pragma unroll
        for (int j = 0; j < 4; j++) { d[j] = (_Float16)x0[j]; d[4 + j] = (_Float16)x1[j]; }
        *(f16x8*)&Xlds[n * 512 + ((chunk ^ (n & 7)) * 8)] = d;
    }
    __syncthreads();

    f32x16 acc[4];
#pragma unroll
    for (int t = 0; t < 4; t++)
#pragma unroll
        for (int r = 0; r < 16; r++) acc[t][r] = 0.f;

    for (int ks = 0; ks < 32; ks++) {
        f16x8 xb = *(const f16x8*)&Xlds[l31 * 512 + (((2 * ks + lhi) ^ (l31 & 7)) * 8)];
#pragma unroll
        for (int ct = 0; ct < 4; ct++) {
            const _Float16* wp = Wvf + ((size_t)ks * 512 + 128 * wave + 32 * ct + l31) * 16 + 8 * lhi;
            acc[ct] = mfma32(*(const f16x8*)wp, xb, acc[ct]);
        }
    }
    const int tile = n0 >> 6;
    const int ksbase = (n0 & 32) >> 4;  // 0 or 2
#pragma unroll
    for (int ct = 0; ct < 4; ct++)
#pragma unroll
        for (int r = 0; r < 16; r++) {
            const int c = 128 * wave + 32 * ct + (r & 3) + 8 * (r >> 2) + 4 * lhi;
            const int ks = ksbase + (l31 >> 4);
            Vf[((size_t)(tile * 4 + ks) * 512 + c) * 16 + (l31 & 15)] = (_Float16)acc[ct][r];
        }
}

// ---- flash15: q=64 + column-split. Grid 512 = 128 q-tiles x 2 img x 2 c-half,
// 512 thr (8 waves), 2 blocks/CU (flash6's overlap) with flash7's q=64 V-reuse:
// per-CU-slot V bytes 512->256 KB. QK duplicated across the c-pair (only 11% of
// MFMA flops; softmax VALU dup). Wave w: QK stream (g=w>>1 tile, b=w&1 q-half),
// both kv-halves a2 sequential (one live sA). PV: wave owns 32 cols
// (256*ch + 32*w) over all 64 q -> acc = 2 x f32x16 (32 regs). Per-wave loads/
// slot = 16 V + 8 K (flash6's proven shape; avoids flash8's load-batch stall).
// Numerics: flash7's per-q-half online merge + flash8's exp2-domain softmax.
__global__ __launch_bounds__(512, 4) void flash15_kernel(
    const _Float16* __restrict__ Q1, const _Float16* __restrict__ Kf1,
    const _Float16* __restrict__ Q2, const _Float16* __restrict__ Kf2,
    const _Float16* __restrict__ Vf1, const _Float16* __restrict__ Vf2,
    const float* __restrict__ im1, const float* __restrict__ im2,
    float* __restrict__ out)
{
    const int bid = blockIdx.x;
    const int img = bid & 1;
    const int chalf = (bid >> 1) & 1;
    const int qbase = (bid >> 2) * 64;
    const _Float16* Q = img ? Q1 : Q2;
    const _Float16* Kf = img ? Kf2 : Kf1;
    const _Float16* Vf = img ? Vf2 : Vf1;
    const float* res = img ? im2 : im1;
    float* o = out + (size_t)img * NN * CC;

    // P[buf][g=tile][chunk=kv>>3][q=64][kv&7] f16, chunk-major = 64 KB
    __shared__ __align__(16) _Float16 P[2][4][8][64][8];
    __shared__ float mPart[2][4][2][64];  // [buf][g][a2][q]
    __shared__ float mF[4][2][64], lF[4][2][64];

    const int tid = threadIdx.x;
    const int lane = tid & 63, w = tid >> 6;
    const int l31 = lane & 31, lhi = lane >> 5;
    const int g = w >> 1, b = w & 1;

    f16x8 qf[4];
    {
        const _Float16* qp = Q + (size_t)(qbase + 32 * b + l31) * DKK + 8 * lhi;
#pragma unroll
        for (int k = 0; k < 4; k++) qf[k] = *(const f16x8*)(qp + 16 * k);
    }

    f32x16 acc[2];  // [qh]: own 32 cols, q-half qh; D row = c_local, col = q = l31
#pragma unroll
    for (int t = 0; t < 2; t++)
#pragma unroll
        for (int r = 0; r < 16; r++) acc[t][r] = 0.f;

    float ma_run[2] = {-3e38f, -3e38f}, l_run[2] = {0.f, 0.f};  // per (g,a2,b) stream
    float mg_run[2] = {-3e38f, -3e38f};                         // acc ref max per qh

    const _Float16* kb = Kf + (size_t)l31 * 16 + 8 * lhi;
    const _Float16* vb = Vf + (size_t)(256 * chalf + 32 * w + l31) * 16 + 8 * lhi;

    // QK for slot s, tile t=4s+g, q-half b: two sequential kv-halves (a2); own
    // running max/sum per (g,a2,b) stream; chunk-major P write. One f32x16 live.
    auto do_qk = [&](int s) {
        const int t = 4 * s + g;
        const int pbuf = s & 1;
#pragma unroll
        for (int a2 = 0; a2 < 2; a2++) {
            f32x16 sA;
#pragma unroll
            for (int r = 0; r < 16; r++) sA[r] = 0.f;
#pragma unroll
            for (int k = 0; k < 4; k++) {
                f16x8 kf = *(const f16x8*)(kb + (size_t)((t * 4 + k) * 64 + 32 * a2) * 16);
                sA = mfma32(kf, qf[k], sA);
            }
            float mr[8];
#pragma unroll
            for (int i = 0; i < 8; i++) mr[i] = fmaxf(sA[i], sA[i + 8]);
#pragma unroll
            for (int i = 0; i < 4; i++) mr[i] = fmaxf(mr[i], mr[i + 4]);
            float mx = fmaxf(fmaxf(mr[0], mr[1]), fmaxf(mr[2], mr[3]));
            mx = fmaxf(mx, __shfl_xor(mx, 32));
            const float manew = fmaxf(ma_run[a2], mx);
            if (lane < 32) mPart[pbuf][g][a2][32 * b + lane] = manew;
            float ls = 0.f;
#pragma unroll
            for (int r = 0; r < 16; r++) {
                float p = exp2fast(sA[r] - manew);
                ls += p;
                sA[r] = p;
            }
            ls += __shfl_xor(ls, 32);
            l_run[a2] = l_run[a2] * exp2fast(ma_run[a2] - manew) + ls;
            ma_run[a2] = manew;
            // kv_local = (r&3) + 8*(r>>2) + 4*lhi + 32*a2 -> chunk 4*a2+(r>>2)
#pragma unroll
            for (int gg = 0; gg < 4; gg++) {
                f16x4 p4;
#pragma unroll
                for (int u = 0; u < 4; u++) p4[u] = (_Float16)sA[gg * 4 + u];
                *(f16x4*)&P[pbuf][g][4 * a2 + gg][32 * b + l31][4 * lhi] = p4;
            }
        }
    };

    do_qk(0);
    __syncthreads();

    for (int s = 0; s < 32; s++) {
        const int pbuf = s & 1;

        // early V-frag issue for PV(s) k=0, all 4 tiles (hides cache latency
        // under QK(s+1))
        f16x8 va0[4];
#pragma unroll
        for (int tt = 0; tt < 4; tt++)
            va0[tt] = *(const f16x8*)(vb + (size_t)((4 * s + tt) * 4 * 512) * 16);

        // pipelined QK for next slot (writes other P buffer)
        if (s < 31) do_qk(s + 1);

        // ---- PV(s): merge all 8 (g,a2) streams online, per q-half
        float f[2][4][2];
        float al[2];
#pragma unroll
        for (int qh = 0; qh < 2; qh++) {
            float mgn = mg_run[qh];
#pragma unroll
            for (int g2 = 0; g2 < 4; g2++)
#pragma unroll
                for (int a2 = 0; a2 < 2; a2++) {
                    f[qh][g2][a2] = mPart[pbuf][g2][a2][32 * qh + l31];
                    mgn = fmaxf(mgn, f[qh][g2][a2]);
                }
            al[qh] = exp2fast(mg_run[qh] - mgn);
            mg_run[qh] = mgn;
#pragma unroll
            for (int g2 = 0; g2 < 4; g2++)
#pragma unroll
                for (int a2 = 0; a2 < 2; a2++)
                    f[qh][g2][a2] = exp2fast(f[qh][g2][a2] - mgn);
        }
        if (!__all((al[0] == 1.f) & (al[1] == 1.f))) {
#pragma unroll
            for (int qh = 0; qh < 2; qh++)
#pragma unroll
                for (int r = 0; r < 16; r++) acc[qh][r] *= al[qh];
        }

#pragma unroll
        for (int tt = 0; tt < 4; tt++)
#pragma unroll
            for (int k = 0; k < 4; k++) {
                // chunk-major P reads: lanes contiguous per half-wave
                f16x8 pb0 = *(const f16x8*)&P[pbuf][tt][2 * k + lhi][l31][0];
                f16x8 pb1 = *(const f16x8*)&P[pbuf][tt][2 * k + lhi][32 + l31][0];
                pb0 = sclh8(pb0, (_Float16)f[0][tt][k >> 1]);
                pb1 = sclh8(pb1, (_Float16)f[1][tt][k >> 1]);
                f16x8 va = (k == 0) ? va0[tt]
                    : *(const f16x8*)(vb + (size_t)(((4 * s + tt) * 4 + k) * 512) * 16);
                acc[0] = mfma32(va, pb0, acc[0]);
                acc[1] = mfma32(va, pb1, acc[1]);
            }
        __syncthreads();  // P(s+1)/mPart(s+1) written by all; P(s) reads done
    }

    // ---- epilogue: per-lane denominator from 8 streams; direct store (each wave
    // owns its 32-col slice over all 64 q)
    if (lane < 32) {
#pragma unroll
        for (int a2 = 0; a2 < 2; a2++) {
            mF[g][a2][32 * b + lane] = ma_run[a2];
            lF[g][a2][32 * b + lane] = l_run[a2];
        }
    }
    __syncthreads();

    float fac[2];
#pragma unroll
    for (int qh = 0; qh < 2; qh++) {
        const int q = 32 * qh + l31;
        const float M = mg_run[qh];  // == max over all 8 stream maxima (exact)
        float den = 0.f;
#pragma unroll
        for (int g2 = 0; g2 < 4; g2++)
#pragma unroll
            for (int a2 = 0; a2 < 2; a2++)
                den += lF[g2][a2][q] * exp2fast(mF[g2][a2][q] - M);
        fac[qh] = 1.f / den;
    }

#pragma unroll
    for (int qh = 0; qh < 2; qh++)
#pragma unroll
        for (int rg = 0; rg < 4; rg++) {
            const int c = 256 * chalf + 32 * w + 8 * rg + 4 * lhi;
            const size_t off = (size_t)(qbase + 32 * qh + l31) * CC + c;
            f32x4 v;
#pragma unroll
            for (int u = 0; u < 4; u++) v[u] = acc[qh][4 * rg + u] * fac[qh];
            f32x4 r4 = *(const f32x4*)(res + off);
            *(f32x4*)(o + off) = v + r4;
        }
}

extern "C" void kernel_launch(void* const* d_in, const int* in_sizes, int n_in,
                              void* d_out, int out_size, void* d_ws, size_t ws_size,
                              hipStream_t stream) {
    const float* im1 = (const float*)d_in[0];
    const float* im2 = (const float*)d_in[1];
    const float* Wq  = (const float*)d_in[2];
    const float* Wk  = (const float*)d_in[3];
    const float* Wv  = (const float*)d_in[4];
    float* out = (float*)d_out;

    _Float16* w = (_Float16*)d_ws;
    _Float16* Wqt = w;                      // 64*512
    _Float16* Wkt = Wqt + 64 * 512;
    _Float16* Wvf = Wkt + 64 * 512;         // 512*512 frag-major
    _Float16* Q1  = Wvf + 512 * 512;        // 8192*64 each
    _Float16* Kf1 = Q1 + NN * DKK;
    _Float16* Q2  = Kf1 + NN * DKK;
    _Float16* Kf2 = Q2 + NN * DKK;
    _Float16* Vf1 = Kf2 + NN * DKK;         // frag-major [128][4][512][16] each
    _Float16* Vf2 = Vf1 + (size_t)CC * NN;

    wtrans_all_kernel<<<1280, 256, 0, stream>>>(Wq, Wk, Wv, Wqt, Wkt, Wvf);
    proj_qk2_kernel<<<dim3(128, 2), 256, 0, stream>>>(im1, im2, Wqt, Wkt, Q1, Kf1, Q2, Kf2);
    proj_vt_kernel<<<dim3(256, 2), 256, 0, stream>>>(im1, im2, Wvf, Vf1, Vf2);
    flash15_kernel<<<512, 512, 0, stream>>>(Q1, Kf1, Q2, Kf2, Vf1, Vf2, im1, im2, out);
}

// Round 6
// 388.678 us; speedup vs baseline: 1.9465x; 1.1305x over previous
//
#include <hip/hip_runtime.h>

#define NN 8192
#define CC 512
#define DKK 64

typedef float f32x4 __attribute__((ext_vector_type(4)));
typedef float f32x16 __attribute__((ext_vector_type(16)));
typedef _Float16 f16x8 __attribute__((ext_vector_type(8)));
typedef _Float16 f16x4 __attribute__((ext_vector_type(4)));

__device__ __forceinline__ f32x4 mfma16(f16x8 a, f16x8 b, f32x4 c) {
    return __builtin_amdgcn_mfma_f32_16x16x32_f16(a, b, c, 0, 0, 0);
}
__device__ __forceinline__ f32x16 mfma32(f16x8 a, f16x8 b, f32x16 c) {
    return __builtin_amdgcn_mfma_f32_32x32x16_f16(a, b, c, 0, 0, 0);
}
__device__ __forceinline__ f16x8 sclh8(f16x8 v, _Float16 h) {
    f16x8 r;
#pragma unroll
    for (int i = 0; i < 8; i++) r[i] = v[i] * h;
    return r;
}
__device__ __forceinline__ float exp2fast(float x) { return __builtin_exp2f(x); }

// ---- all weight transposes in one launch. grid 1280 x 256.
__global__ void wtrans_all_kernel(const float* __restrict__ Wq, const float* __restrict__ Wk,
                                  const float* __restrict__ Wv,
                                  _Float16* __restrict__ Wqt, _Float16* __restrict__ Wkt,
                                  _Float16* __restrict__ Wvf) {
    int idx = blockIdx.x * 256 + threadIdx.x;
    if (idx < 32768) {
        int n = idx >> 9, k = idx & 511;
        Wqt[idx] = (_Float16)Wq[k * 64 + n];
    } else if (idx < 65536) {
        int j = idx - 32768;
        int n = j >> 9, k = j & 511;
        Wkt[j] = (_Float16)Wk[k * 64 + n];
    } else {
        int j = idx - 65536;
        int k16 = j & 15, c = (j >> 4) & 511, ks = j >> 13;
        Wvf[j] = (_Float16)Wv[(size_t)(16 * ks + k16) * 512 + c];
    }
}

// ---- fused Q+K projection: Q[N][64] row-major f16 (PRE-SCALED by log2(e): flash
// softmax runs in the exp2 domain); K -> frag-major Kf[tile][ks][kv6][k16]
__global__ __launch_bounds__(256) void proj_qk2_kernel(
    const float* __restrict__ im1, const float* __restrict__ im2,
    const _Float16* __restrict__ Wqt, const _Float16* __restrict__ Wkt,
    _Float16* __restrict__ Q1, _Float16* __restrict__ Kf1,
    _Float16* __restrict__ Q2, _Float16* __restrict__ Kf2)
{
    const float* X = blockIdx.y ? im2 : im1;
    _Float16* Q = blockIdx.y ? Q2 : Q1;
    _Float16* Kf = blockIdx.y ? Kf2 : Kf1;

    __shared__ __align__(16) _Float16 Wlds[128 * 512];  // 128 KB

    const int tid = threadIdx.x;
    const int lane = tid & 63, wave = tid >> 6;
    const int n16 = lane & 15, quad = lane >> 4;

#pragma unroll
    for (int i = 0; i < 32; i++) {
        const int idx = tid + 256 * i;
        const int row = idx >> 6, ch = idx & 63;
        const _Float16* src = (row < 64) ? (Wqt + (size_t)row * 512 + ch * 8)
                                         : (Wkt + (size_t)(row - 64) * 512 + ch * 8);
        *(f16x8*)&Wlds[row * 512 + ((ch ^ (row & 7)) * 8)] = *(const f16x8*)src;
    }
    __syncthreads();

    const int arow = blockIdx.x * 64 + wave * 16 + n16;
    f32x4 acc[8];
#pragma unroll
    for (int i = 0; i < 8; i++) acc[i] = (f32x4){0.f, 0.f, 0.f, 0.f};

    const float* xbase = X + (size_t)arow * 512 + quad * 8;
    for (int kk = 0; kk < 16; kk++) {
        f32x4 xa = *(const f32x4*)(xbase + kk * 32);
        f32x4 xb = *(const f32x4*)(xbase + kk * 32 + 4);
        f16x8 afrag;
#pragma unroll
        for (int j = 0; j < 4; j++) { afrag[j] = (_Float16)xa[j]; afrag[4 + j] = (_Float16)xb[j]; }
#pragma unroll
        for (int t = 0; t < 8; t++) {
            const int row = t * 16 + n16;
            f16x8 bfr = *(const f16x8*)&Wlds[row * 512 + (((4 * kk + quad) ^ (row & 7)) * 8)];
            acc[t] = mfma16(afrag, bfr, acc[t]);
        }
    }
    const int rbase = blockIdx.x * 64 + wave * 16 + quad * 4;
#pragma unroll
    for (int t = 0; t < 4; t++)
#pragma unroll
        for (int r = 0; r < 4; r++) {
            Q[(size_t)(rbase + r) * 64 + t * 16 + n16] = (_Float16)(acc[t][r] * 1.44269504f);
            Kf[((size_t)(blockIdx.x * 4 + t) * 64 + (wave * 16 + quad * 4 + r)) * 16 + n16] =
                (_Float16)acc[4 + t][r];
        }
}

// ---- V projection -> frag-major Vf[tile][ks=n6>>4][c=512][n16]
__global__ __launch_bounds__(256) void proj_vt_kernel(
    const float* __restrict__ im1, const float* __restrict__ im2,
    const _Float16* __restrict__ Wvf,
    _Float16* __restrict__ Vf1, _Float16* __restrict__ Vf2)
{
    const float* X = blockIdx.y ? im2 : im1;
    _Float16* Vf = blockIdx.y ? Vf2 : Vf1;
    const int n0 = blockIdx.x * 32;
    const int tid = threadIdx.x;
    const int lane = tid & 63, wave = tid >> 6;
    const int l31 = lane & 31, lhi = lane >> 5;

    __shared__ __align__(16) _Float16 Xlds[32 * 512];

#pragma unroll
    for (int i = 0; i < 8; i++) {
        const int n = tid >> 3;
        const int chunk = (tid & 7) + 8 * i;
        const float* xp = X + (size_t)(n0 + n) * CC + chunk * 8;
        f32x4 x0 = *(const f32x4*)xp;
        f32x4 x1 = *(const f32x4*)(xp + 4);
        f16x8 d;
#pragma unroll
        for (int j = 0; j < 4; j++) { d[j] = (_Float16)x0[j]; d[4 + j] = (_Float16)x1[j]; }
        *(f16x8*)&Xlds[n * 512 + ((chunk ^ (n & 7)) * 8)] = d;
    }
    __syncthreads();

    f32x16 acc[4];
#pragma unroll
    for (int t = 0; t < 4; t++)
#pragma unroll
        for (int r = 0; r < 16; r++) acc[t][r] = 0.f;

    for (int ks = 0; ks < 32; ks++) {
        f16x8 xb = *(const f16x8*)&Xlds[l31 * 512 + (((2 * ks + lhi) ^ (l31 & 7)) * 8)];
#pragma unroll
        for (int ct = 0; ct < 4; ct++) {
            const _Float16* wp = Wvf + ((size_t)ks * 512 + 128 * wave + 32 * ct + l31) * 16 + 8 * lhi;
            acc[ct] = mfma32(*(const f16x8*)wp, xb, acc[ct]);
        }
    }
    const int tile = n0 >> 6;
    const int ksbase = (n0 & 32) >> 4;  // 0 or 2
#pragma unroll
    for (int ct = 0; ct < 4; ct++)
#pragma unroll
        for (int r = 0; r < 16; r++) {
            const int c = 128 * wave + 32 * ct + (r & 3) + 8 * (r >> 2) + 4 * lhi;
            const int ks = ksbase + (l31 >> 4);
            Vf[((size_t)(tile * 4 + ks) * 512 + c) * 16 + (l31 & 15)] = (_Float16)acc[ct][r];
        }
}

// ---- flash17: V through LDS (T14 async-STAGE), 1-tile slots. q=64, 1024 thr
// (16 waves), grid 256, 1 blk/CU. Slot = 64 kv, 128 slots. Per slot each wave:
// issue 4 global loads (4 KB share of NEXT V tile) -> regs; waves 0-3 (one/SIMD,
// (a=kv-half, b=q-half)) compute QK(s+1) from prefetched K regs + softmax
// (2 streams/q); all 16 waves PV(s): V via conflict-free ds_read_b128 (LDS,
// ~12cy) + P LDS reads, 8 mfma32 (wave owns 32 cols x 64 q, acc = 2 x f32x16);
// ds_write staged V; 1 barrier/slot. V global latency hidden under full slot.
// LDS: V dbuf 128K + P dbuf 16K + softmax 2K = 149 KB.
__global__ __launch_bounds__(1024, 4) void flash17_kernel(
    const _Float16* __restrict__ Q1, const _Float16* __restrict__ Kf1,
    const _Float16* __restrict__ Q2, const _Float16* __restrict__ Kf2,
    const _Float16* __restrict__ Vf1, const _Float16* __restrict__ Vf2,
    const float* __restrict__ im1, const float* __restrict__ im2,
    float* __restrict__ out)
{
    const int bid = blockIdx.x;
    const int img = bid & 1;
    const int qbase = (bid >> 1) * 64;
    const _Float16* Q = img ? Q1 : Q2;
    const _Float16* Kf = img ? Kf2 : Kf1;
    const _Float16* Vf = img ? Vf2 : Vf1;
    const float* res = img ? im2 : im1;
    float* o = out + (size_t)img * NN * CC;

    __shared__ __align__(16) _Float16 Vs[2][4 * 512 * 16];  // [buf][ks*8192+c*16+k16] 128 KB
    __shared__ __align__(16) _Float16 P[2][8][64][8];       // [buf][chunk][q][fine] 16 KB
    __shared__ float mPart[2][2][64];                       // [buf][a][q]
    __shared__ float mF[2][64], lF[2][64];

    const int tid = threadIdx.x;
    const int lane = tid & 63, w = tid >> 6;
    const int l31 = lane & 31, lhi = lane >> 5;
    const bool isqk = (w < 4);
    const int a = w & 1, b = (w >> 1) & 1;

    // ---- PV state: wave owns cols 32w..32w+31 over 64 q (2 q-halves)
    f32x16 acc[2];
#pragma unroll
    for (int t = 0; t < 2; t++)
#pragma unroll
        for (int r = 0; r < 16; r++) acc[t][r] = 0.f;
    float mg_run[2] = {-3e38f, -3e38f};

    // ---- QK state (waves 0-3 only): stream = kv-half a, q-half b
    f16x8 qf[4], kreg[4];
    float ma_run = -3e38f, l_run = 0.f;

    const _Float16* kb = Kf + (size_t)(32 * a + l31) * 16 + 8 * lhi;

    if (isqk) {
        const _Float16* qp = Q + (size_t)(qbase + 32 * b + l31) * DKK + 8 * lhi;
#pragma unroll
        for (int k = 0; k < 4; k++) qf[k] = *(const f16x8*)(qp + 16 * k);
#pragma unroll
        for (int k = 0; k < 4; k++) kreg[k] = *(const f16x8*)(kb + (size_t)k * 1024);
    }

    // staged V regs (4 x 1KB wave-chunks; wave share = [w*2048, w*2048+2048) elems)
    f16x8 st0, st1, st2, st3;
    auto stage_issue = [&](int t) {
        const _Float16* src = Vf + (size_t)t * 32768 + w * 2048 + lane * 8;
        st0 = *(const f16x8*)(src);
        st1 = *(const f16x8*)(src + 512);
        st2 = *(const f16x8*)(src + 1024);
        st3 = *(const f16x8*)(src + 1536);
    };
    auto stage_write = [&](int t) {
        _Float16* dst = &Vs[t & 1][0] + w * 2048 + lane * 8;
        *(f16x8*)(dst) = st0;
        *(f16x8*)(dst + 512) = st1;
        *(f16x8*)(dst + 1024) = st2;
        *(f16x8*)(dst + 1536) = st3;
    };

    // QK for tile tt: consumes kreg (K of tile tt), issues kreg loads for tt+1.
    auto do_qk = [&](int tt) {
        const int pbuf = tt & 1;
        f32x16 sA;
#pragma unroll
        for (int r = 0; r < 16; r++) sA[r] = 0.f;
#pragma unroll
        for (int k = 0; k < 4; k++) sA = mfma32(kreg[k], qf[k], sA);
        if (tt + 1 < 128) {
#pragma unroll
            for (int k = 0; k < 4; k++)
                kreg[k] = *(const f16x8*)(kb + (size_t)((tt + 1) * 4 + k) * 1024);
        }
        float mr[8];
#pragma unroll
        for (int i = 0; i < 8; i++) mr[i] = fmaxf(sA[i], sA[i + 8]);
#pragma unroll
        for (int i = 0; i < 4; i++) mr[i] = fmaxf(mr[i], mr[i + 4]);
        float mx = fmaxf(fmaxf(mr[0], mr[1]), fmaxf(mr[2], mr[3]));
        mx = fmaxf(mx, __shfl_xor(mx, 32));
        const float manew = fmaxf(ma_run, mx);
        if (lane < 32) mPart[pbuf][a][32 * b + lane] = manew;
        float ls = 0.f;
#pragma unroll
        for (int r = 0; r < 16; r++) {
            float p = exp2fast(sA[r] - manew);
            ls += p;
            sA[r] = p;
        }
        ls += __shfl_xor(ls, 32);
        l_run = l_run * exp2fast(ma_run - manew) + ls;
        ma_run = manew;
        // kv_local = (r&3) + 8*(r>>2) + 4*lhi + 32*a -> chunk 4a+(r>>2)
#pragma unroll
        for (int gg = 0; gg < 4; gg++) {
            f16x4 p4;
#pragma unroll
            for (int u = 0; u < 4; u++) p4[u] = (_Float16)sA[gg * 4 + u];
            *(f16x4*)&P[pbuf][4 * a + gg][32 * b + l31][4 * lhi] = p4;
        }
    };

    // ---- prologue: K(0)+QK(0) by QK waves; V(0) staged by all; one barrier
    stage_issue(0);
    if (isqk) do_qk(0);
    stage_write(0);
    __syncthreads();

    for (int s = 0; s < 128; s++) {
        const int pbuf = s & 1;
        if (s < 127) {
            stage_issue(s + 1);           // V(s+1) global loads in flight
            if (isqk) do_qk(s + 1);       // writes P[(s+1)&1], mPart[(s+1)&1]
        }

        // ---- merge 2 streams per q-half, then PV(s) from LDS
        float f[2][2], al[2];
#pragma unroll
        for (int qh = 0; qh < 2; qh++) {
            float mgn = mg_run[qh];
#pragma unroll
            for (int a2 = 0; a2 < 2; a2++) {
                f[qh][a2] = mPart[pbuf][a2][32 * qh + l31];
                mgn = fmaxf(mgn, f[qh][a2]);
            }
            al[qh] = exp2fast(mg_run[qh] - mgn);
            mg_run[qh] = mgn;
#pragma unroll
            for (int a2 = 0; a2 < 2; a2++) f[qh][a2] = exp2fast(f[qh][a2] - mgn);
        }
        if (!__all((al[0] == 1.f) & (al[1] == 1.f))) {
#pragma unroll
            for (int qh = 0; qh < 2; qh++)
#pragma unroll
                for (int r = 0; r < 16; r++) acc[qh][r] *= al[qh];
        }

        const _Float16* vbufp = &Vs[pbuf][0];
#pragma unroll
        for (int ks = 0; ks < 4; ks++) {
            f16x8 va = *(const f16x8*)(vbufp + ks * 8192 + (32 * w + l31) * 16 + 8 * lhi);
            f16x8 pb0 = *(const f16x8*)&P[pbuf][2 * ks + lhi][l31][0];
            f16x8 pb1 = *(const f16x8*)&P[pbuf][2 * ks + lhi][32 + l31][0];
            pb0 = sclh8(pb0, (_Float16)f[0][ks >> 1]);
            pb1 = sclh8(pb1, (_Float16)f[1][ks >> 1]);
            acc[0] = mfma32(va, pb0, acc[0]);
            acc[1] = mfma32(va, pb1, acc[1]);
        }

        if (s < 127) stage_write(s + 1);  // V(s+1) -> other buffer (waits vmcnt)
        __syncthreads();                  // P/mPart(s+1) + V(s+1) visible; P(s)/V(s) reads done
    }

    // ---- epilogue: 2-stream denominator; direct store with residual
    if (isqk && lane < 32) {
        mF[a][32 * b + lane] = ma_run;
        lF[a][32 * b + lane] = l_run;
    }
    __syncthreads();

    float fac[2];
#pragma unroll
    for (int qh = 0; qh < 2; qh++) {
        const int q = 32 * qh + l31;
        const float M = mg_run[qh];  // == max over both streams' final maxima
        float den = 0.f;
#pragma unroll
        for (int a2 = 0; a2 < 2; a2++)
            den += lF[a2][q] * exp2fast(mF[a2][q] - M);
        fac[qh] = 1.f / den;
    }

#pragma unroll
    for (int qh = 0; qh < 2; qh++)
#pragma unroll
        for (int rg = 0; rg < 4; rg++) {
            const int c = 32 * w + 8 * rg + 4 * lhi;
            const size_t off = (size_t)(qbase + 32 * qh + l31) * CC + c;
            f32x4 v;
#pragma unroll
            for (int u = 0; u < 4; u++) v[u] = acc[qh][4 * rg + u] * fac[qh];
            f32x4 r4 = *(const f32x4*)(res + off);
            *(f32x4*)(o + off) = v + r4;
        }
}

extern "C" void kernel_launch(void* const* d_in, const int* in_sizes, int n_in,
                              void* d_out, int out_size, void* d_ws, size_t ws_size,
                              hipStream_t stream) {
    const float* im1 = (const float*)d_in[0];
    const float* im2 = (const float*)d_in[1];
    const float* Wq  = (const float*)d_in[2];
    const float* Wk  = (const float*)d_in[3];
    const float* Wv  = (const float*)d_in[4];
    float* out = (float*)d_out;

    _Float16* w = (_Float16*)d_ws;
    _Float16* Wqt = w;                      // 64*512
    _Float16* Wkt = Wqt + 64 * 512;
    _Float16* Wvf = Wkt + 64 * 512;         // 512*512 frag-major
    _Float16* Q1  = Wvf + 512 * 512;        // 8192*64 each
    _Float16* Kf1 = Q1 + NN * DKK;
    _Float16* Q2  = Kf1 + NN * DKK;
    _Float16* Kf2 = Q2 + NN * DKK;
    _Float16* Vf1 = Kf2 + NN * DKK;         // frag-major [128][4][512][16] each
    _Float16* Vf2 = Vf1 + (size_t)CC * NN;

    wtrans_all_kernel<<<1280, 256, 0, stream>>>(Wq, Wk, Wv, Wqt, Wkt, Wvf);
    proj_qk2_kernel<<<dim3(128, 2), 256, 0, stream>>>(im1, im2, Wqt, Wkt, Q1, Kf1, Q2, Kf2);
    proj_vt_kernel<<<dim3(256, 2), 256, 0, stream>>>(im1, im2, Wvf, Vf1, Vf2);
    flash17_kernel<<<256, 1024, 0, stream>>>(Q1, Kf1, Q2, Kf2, Vf1, Vf2, im1, im2, out);
}